// Round 9
// baseline (163.949 us; speedup 1.0000x reference)
//
#include <hip/hip_runtime.h>
#include <hip/hip_bf16.h>
#include <stdint.h>

#define D_MODEL 1024
#define NHEADS  16
#define DKH     64
#define BATCH   2
#define SEQ     2048
#define MTOT    (BATCH*SEQ)   // 4096

typedef __attribute__((ext_vector_type(8)))  short bf16x8;   // 8 bf16 = 4 VGPRs
typedef __attribute__((ext_vector_type(4)))  float f32x4;
typedef __attribute__((ext_vector_type(16))) float f32x16;
typedef __attribute__((ext_vector_type(4)))  unsigned int u32x4;

__device__ inline unsigned short f2bf(float f) {
    __hip_bfloat16 h = __float2bfloat16(f);
    return *reinterpret_cast<unsigned short*>(&h);
}
__device__ inline unsigned int pack2bf(float a, float b) {   // low=a, high=b (RNE)
    __hip_bfloat162 h = __float22bfloat162_rn(float2{a, b});
    return *reinterpret_cast<unsigned int*>(&h);
}

// async global->LDS, 16B per lane; LDS dest = wave-uniform base + lane*16 (m97/m104)
__device__ inline void gl2lds16(const unsigned short* g, unsigned short* l) {
    __builtin_amdgcn_global_load_lds(
        (const __attribute__((address_space(1))) void*)g,
        (__attribute__((address_space(3))) void*)l,
        16, 0, 0);
}

// One-shot fp32 -> bf16 conversion of x and the 4 weight matrices.
__global__ __launch_bounds__(256) void cvt_all(
    const float* __restrict__ x,  const float* __restrict__ wq,
    const float* __restrict__ wk, const float* __restrict__ wv,
    const float* __restrict__ wo,
    unsigned short* __restrict__ xb,  unsigned short* __restrict__ wqb,
    unsigned short* __restrict__ wkb, unsigned short* __restrict__ wvb,
    unsigned short* __restrict__ wob)
{
    int bid = blockIdx.x;
    const float* s; unsigned short* d; size_t base;
    if (bid < 2048) { s = x; d = xb; base = (size_t)bid * 2048; }
    else {
        int w  = (bid - 2048) >> 9;
        int wb = (bid - 2048) & 511;
        s = (w == 0) ? wq : (w == 1) ? wk : (w == 2) ? wv : wo;
        d = (w == 0) ? wqb : (w == 1) ? wkb : (w == 2) ? wvb : wob;
        base = (size_t)wb * 2048;
    }
    size_t i = base + (size_t)threadIdx.x * 8;
    float4 a = *(const float4*)(s + i);
    float4 b = *(const float4*)(s + i + 4);
    unsigned short t8[8] = {f2bf(a.x), f2bf(a.y), f2bf(a.z), f2bf(a.w),
                            f2bf(b.x), f2bf(b.y), f2bf(b.z), f2bf(b.w)};
    *(uint4*)(d + i) = *(uint4*)t8;
}

// Fused QKV projection, 128(M)x64(N) tiles, 256 thr, grid 512 = 2 BLOCKS/CU.
// Empirical law from r0-r8: per-CU staging rate ~9.6 B/cyc per resident block
// (x1.5-1.6 at 2-3 blocks). r3-r8's 256-block grid pinned qkv at 1 block/CU
// = 46.5us across FOUR sync structures. This trades +25% staged bytes
// (x-stripe duplicated x16) for the 2-block rate: 327MB/(256CU*15B/cyc)
// ~ 33-37us. Simple 2-phase __syncthreads pipeline (m114 cross-block overlap
// does the latency hiding; counted-vmcnt measured worthless here).
// Wave tile 32(M)x64(N); x staged once for Q, K, V^T (in-block VSWAP).
__global__ __launch_bounds__(256, 2) void qkv_fused(
    const unsigned short* __restrict__ X,
    const unsigned short* __restrict__ Wq,
    const unsigned short* __restrict__ Wk,
    const unsigned short* __restrict__ Wv,
    unsigned short* __restrict__ Qo,
    unsigned short* __restrict__ Ko,
    unsigned short* __restrict__ Vto,
    float qscale)
{
    const int id = blockIdx.x;                    // 512 blocks, 512%8==0
    const int sw = (id & 7) * 64 + (id >> 3);     // XCD c -> sw chunk [64c,64c+64)
    const int mi = sw >> 4, ni = sw & 15;         // per XCD: 4 x-stripes, all ni
    const int m0 = mi * 128, n0 = ni * 64;

    __shared__ __align__(16) unsigned short Xs[2][128 * 32];  // 16 KiB
    __shared__ __align__(16) unsigned short Bq[2][64 * 32];   //  8 KiB
    __shared__ __align__(16) unsigned short Bk[2][64 * 32];
    __shared__ __align__(16) unsigned short Bv[2][64 * 32];   // 40 KiB total

    const int t = threadIdx.x;
    const int wave = t >> 6, lane = t & 63;
    const int quad = lane >> 4, l16 = lane & 15;
    const int wm = wave * 32;                     // wave's 32 x-rows

    // 20 staging loads/step (16 rows each): q = wave*5 + s
    //   q 0-7: Xs rows 16q | 8-11: Bq | 12-15: Bk | 16-19: Bv
    const int srow = lane >> 2;                   // 0..15
    const int schk = (lane & 3) * 8;              // shorts
    const unsigned short* SgA[5];
    unsigned short* Ld0[5];
    unsigned short* Ld1[5];
    #pragma unroll
    for (int s = 0; s < 5; ++s) {
        const int q = wave * 5 + s;
        const unsigned short* gsrc; int grow; unsigned short *l0, *l1; int lrow;
        if (q < 8)       { gsrc = X;  grow = m0 + q * 16;        l0 = &Xs[0][0]; l1 = &Xs[1][0]; lrow = q * 16; }
        else if (q < 12) { gsrc = Wq; grow = n0 + (q - 8) * 16;  l0 = &Bq[0][0]; l1 = &Bq[1][0]; lrow = (q - 8) * 16; }
        else if (q < 16) { gsrc = Wk; grow = n0 + (q - 12) * 16; l0 = &Bk[0][0]; l1 = &Bk[1][0]; lrow = (q - 12) * 16; }
        else             { gsrc = Wv; grow = n0 + (q - 16) * 16; l0 = &Bv[0][0]; l1 = &Bv[1][0]; lrow = (q - 16) * 16; }
        SgA[s] = gsrc + (size_t)(grow + srow) * D_MODEL + schk;
        Ld0[s] = l0 + lrow * 32;    // lane*16B added by HW
        Ld1[s] = l1 + lrow * 32;
    }

    f32x4 aQ[2][4] = {}, aK[2][4] = {}, aV[4][2] = {};

#define QKV_STAGE(BUF, K0)                                                    \
    do {                                                                      \
        _Pragma("unroll")                                                     \
        for (int s = 0; s < 5; ++s)                                           \
            gl2lds16(SgA[s] + (K0), (BUF) ? Ld1[s] : Ld0[s]);                 \
    } while (0)

#define QKV_COMP(BUF)                                                         \
    do {                                                                      \
        bf16x8 xa[2], fq[4], fk[4], fv[4];                                    \
        _Pragma("unroll")                                                     \
        for (int i = 0; i < 2; ++i)                                           \
            xa[i] = *(const bf16x8*)(&Xs[(BUF)][0] + (wm + i * 16 + l16) * 32 + quad * 8); \
        _Pragma("unroll")                                                     \
        for (int j = 0; j < 4; ++j) {                                         \
            fq[j] = *(const bf16x8*)(&Bq[(BUF)][0] + (j * 16 + l16) * 32 + quad * 8); \
            fk[j] = *(const bf16x8*)(&Bk[(BUF)][0] + (j * 16 + l16) * 32 + quad * 8); \
            fv[j] = *(const bf16x8*)(&Bv[(BUF)][0] + (j * 16 + l16) * 32 + quad * 8); \
        }                                                                     \
        _Pragma("unroll")                                                     \
        for (int i = 0; i < 2; ++i)                                           \
            _Pragma("unroll")                                                 \
            for (int j = 0; j < 4; ++j) {                                     \
                aQ[i][j] = __builtin_amdgcn_mfma_f32_16x16x32_bf16(xa[i], fq[j], aQ[i][j], 0, 0, 0); \
                aK[i][j] = __builtin_amdgcn_mfma_f32_16x16x32_bf16(xa[i], fk[j], aK[i][j], 0, 0, 0); \
                aV[j][i] = __builtin_amdgcn_mfma_f32_16x16x32_bf16(fv[j], xa[i], aV[j][i], 0, 0, 0); \
            }                                                                 \
    } while (0)

    QKV_STAGE(0, 0);
    __syncthreads();
    #pragma unroll 2
    for (int step = 0; step < 32; ++step) {       // K-step = 32
        const int cur = step & 1;
        if (step + 1 < 32) QKV_STAGE(cur ^ 1, (step + 1) * 32);  // issue first
        QKV_COMP(cur);
        __syncthreads();                          // drain + WAR guard
    }
#undef QKV_STAGE
#undef QKV_COMP

    #pragma unroll
    for (int i = 0; i < 2; ++i)
        #pragma unroll
        for (int j = 0; j < 4; ++j)
            #pragma unroll
            for (int r = 0; r < 4; ++r) {
                const int mr = m0 + wm + i * 16 + quad * 4 + r;
                const int nc = n0 + j * 16 + l16;
                Qo[(size_t)mr * D_MODEL + nc] = f2bf(aQ[i][j][r] * qscale);
                Ko[(size_t)mr * D_MODEL + nc] = f2bf(aK[i][j][r]);
                // V^T: row = weight-side of aV, col = x-side
                Vto[(size_t)(n0 + j * 16 + quad * 4 + r) * MTOT
                    + (m0 + wm + i * 16 + l16)] = f2bf(aV[j][i][r]);
            }
}

// Output projection C_fp32[M,N] = A[M,K] @ W[N,K]^T, 128^2 tile, 512 thr,
// depth-2 counted-vmcnt pipeline, literal buffer indices (r8, ~21us;
// staging-bound at 128MB — re-tiling to 2 blocks/CU adds exactly the bytes
// the rate gain recovers, so left unchanged).
__global__ __launch_bounds__(512, 2) void gemm_o(
    const unsigned short* __restrict__ A,
    const unsigned short* __restrict__ W,
    float* __restrict__ C)
{
    const int id = blockIdx.x + 32 * blockIdx.y;
    const int sw = (id & 7) * 32 + (id >> 3);
    const int m0 = (sw & 31) * 128, n0 = (sw >> 5) * 128;

    __shared__ __align__(16) unsigned short As[3][128 * 32];
    __shared__ __align__(16) unsigned short Bs[3][128 * 32];   // 48 KiB

    const int t = threadIdx.x, wave = t >> 6, lane = t & 63;
    const int quad = lane >> 4, l16 = lane & 15;
    const int wm = (wave >> 2) * 64, wn = (wave & 3) * 32;

    const int stile = wave >> 2;
    const int srow  = (wave & 3) * 32 + (lane >> 2);
    const int schk  = (lane & 3) * 8;
    const unsigned short* Sg = (stile ? W : A)
        + (size_t)((stile ? n0 : m0) + srow) * D_MODEL + schk;
    unsigned short* LdB = (stile ? &Bs[0][0] : &As[0][0]) + (wave & 3) * 32 * 32;

    f32x4 acc[4][2] = {};

#define O_STAGE(BUF, STEP)                                                    \
    do {                                                                      \
        _Pragma("unroll")                                                     \
        for (int g = 0; g < 2; ++g)                                           \
            gl2lds16(Sg + (STEP) * 32 + (size_t)g * 16 * D_MODEL,             \
                     LdB + (BUF) * 4096 + g * 512);                           \
    } while (0)

#define O_COMP(BUF)                                                           \
    do {                                                                      \
        bf16x8 af[4], bfr[2];                                                 \
        _Pragma("unroll")                                                     \
        for (int i = 0; i < 4; ++i)                                           \
            af[i] = *(const bf16x8*)(&As[(BUF)][0] + (wm + i * 16 + l16) * 32 + quad * 8); \
        _Pragma("unroll")                                                     \
        for (int j = 0; j < 2; ++j)                                           \
            bfr[j] = *(const bf16x8*)(&Bs[(BUF)][0] + (wn + j * 16 + l16) * 32 + quad * 8); \
        _Pragma("unroll")                                                     \
        for (int i = 0; i < 4; ++i)                                           \
            _Pragma("unroll")                                                 \
            for (int j = 0; j < 2; ++j)                                       \
                acc[i][j] = __builtin_amdgcn_mfma_f32_16x16x32_bf16(af[i], bfr[j], acc[i][j], 0, 0, 0); \
    } while (0)

#define O_STEP(CBUF, SBUF, STEP)                                              \
    do {                                                                      \
        __builtin_amdgcn_s_barrier();                                         \
        O_STAGE(SBUF, (STEP) + 2);                                            \
        asm volatile("s_waitcnt vmcnt(4)" ::: "memory");                      \
        __builtin_amdgcn_s_barrier();                                         \
        __builtin_amdgcn_sched_barrier(0);                                    \
        O_COMP(CBUF);                                                         \
    } while (0)

    O_STAGE(0, 0);
    O_STAGE(1, 1);
    for (int s3 = 0; s3 < 30; s3 += 3) {
        O_STEP(0, 2, s3);
        O_STEP(1, 0, s3 + 1);
        O_STEP(2, 1, s3 + 2);
    }
    __builtin_amdgcn_s_barrier();
    asm volatile("s_waitcnt vmcnt(2)" ::: "memory");
    __builtin_amdgcn_s_barrier();
    __builtin_amdgcn_sched_barrier(0);
    O_COMP(0);
    __builtin_amdgcn_s_barrier();
    asm volatile("s_waitcnt vmcnt(0)" ::: "memory");
    __builtin_amdgcn_s_barrier();
    __builtin_amdgcn_sched_barrier(0);
    O_COMP(1);
#undef O_STEP
#undef O_STAGE
#undef O_COMP

    #pragma unroll
    for (int i = 0; i < 4; ++i)
        #pragma unroll
        for (int j = 0; j < 2; ++j)
            #pragma unroll
            for (int r = 0; r < 4; ++r)
                C[(size_t)(m0 + wm + i * 16 + quad * 4 + r) * D_MODEL
                  + n0 + wn + j * 16 + l16] = acc[i][j][r];
}

// Flash causal attention — r5-exact verified kernel (64-q blocks, split-key
// waves, 2-barrier tile loop, 18 KiB LDS, 256 thr, grid (32,32) balanced).
__global__ __launch_bounds__(256, 4) void attn_kernel(
    const unsigned short* __restrict__ Qm,
    const unsigned short* __restrict__ Km,
    const unsigned short* __restrict__ VtG,
    unsigned short* __restrict__ Om)
{
    const int bh = blockIdx.x;
    const int y  = blockIdx.y, g = y & 7, sl = y >> 3;
    const int qt = (sl == 0) ? 31 - g : (sl == 1) ? 16 + g : (sl == 2) ? 15 - g : g;
    const int h  = bh & 15;
    const int b  = bh >> 4;
    const int t     = threadIdx.x;
    const int wave  = t >> 6, lane = t & 63;
    const int qhalf = wave >> 1, khalf = wave & 1;
    const int l31   = lane & 31, h32 = lane >> 5;

    __shared__ __align__(16) unsigned short Ks[64 * 72];      // K tile [key][dk]
    __shared__ __align__(16) unsigned short Vt[64 * 72];      // V^T tile [dk][key]

    const size_t base = (size_t)b * SEQ * D_MODEL + (size_t)h * DKH;
    const unsigned short* Qh = Qm + base;
    const unsigned short* Kh = Km + base;
    const unsigned short* Vh = VtG + (size_t)h * DKH * MTOT + (size_t)b * SEQ;  // [dk][m]

    const int qrow = qt * 64 + qhalf * 32 + l31;
    bf16x8 qf[4];
    #pragma unroll
    for (int ks = 0; ks < 4; ++ks)
        qf[ks] = *(const bf16x8*)(Qh + (size_t)qrow * D_MODEL + ks * 16 + h32 * 8);

    f32x16 accOT[2] = {};   // O^T partial: col=l31=q, row=(reg&3)+8*(reg>>2)+4*h32=dk (+32*db)
    float  la[4] = {0.f, 0.f, 0.f, 0.f};   // 4-way split row-sum partials

    const int srow = t >> 2, scol = (t & 3) * 16;
    const int kbase = khalf * 32;

    uint4 kr0, kr1, vr0, vr1;
    {
        const unsigned short* ks = Kh + (size_t)srow * D_MODEL + scol;
        kr0 = *(const uint4*)ks; kr1 = *(const uint4*)(ks + 8);
        const unsigned short* vs = Vh + (size_t)srow * MTOT + scol;
        vr0 = *(const uint4*)vs; vr1 = *(const uint4*)(vs + 8);
    }

    for (int kt = 0; kt <= qt; ++kt) {
        __syncthreads();   // prior iter's frag reads done
        *(uint4*)(Ks + srow * 72 + scol)     = kr0;
        *(uint4*)(Ks + srow * 72 + scol + 8) = kr1;
        *(uint4*)(Vt + srow * 72 + scol)     = vr0;
        *(uint4*)(Vt + srow * 72 + scol + 8) = vr1;
        __syncthreads();

        if (kt < qt) {     // prefetch next tile; overlaps compute below
            const unsigned short* ks = Kh + (size_t)((kt + 1) * 64 + srow) * D_MODEL + scol;
            kr0 = *(const uint4*)ks; kr1 = *(const uint4*)(ks + 8);
            const unsigned short* vs = Vh + (size_t)srow * MTOT + (kt + 1) * 64 + scol;
            vr0 = *(const uint4*)vs; vr1 = *(const uint4*)(vs + 8);
        }

        const bool diag = (kt == qt);
        if (diag && khalf > qhalf) continue;   // fully-masked quarter: skip

        f32x16 sT = {};
        #pragma unroll
        for (int ks = 0; ks < 4; ++ks) {
            bf16x8 kf = *(const bf16x8*)(Ks + (kbase + l31) * 72 + ks * 16 + h32 * 8);
            sT = __builtin_amdgcn_mfma_f32_32x32x16_bf16(kf, qf[ks], sT, 0, 0, 0);
        }

        const bool maskq = diag && (khalf == qhalf);
        float pv[16];
        #pragma unroll
        for (int reg = 0; reg < 16; ++reg) {
            const int rloc = (reg & 3) + 8 * (reg >> 2) + 4 * h32;   // key_local
            float v = sT[reg];
            if (maskq) v = (rloc <= l31) ? v : -1e30f;
            float p = exp2f(v);
            la[reg & 3] += p;
            pv[reg] = p;
        }
        unsigned int pk[8], pr[8];
        #pragma unroll
        for (int i = 0; i < 8; ++i) pk[i] = pack2bf(pv[2 * i], pv[2 * i + 1]);
        #pragma unroll
        for (int i = 0; i < 8; ++i) pr[i] = __shfl_xor(pk[i], 32, 64);

        #pragma unroll
        for (int ks2 = 0; ks2 < 2; ++ks2) {
            union { u32x4 u; bf16x8 b; } pf;
            pf.u[0] = h32 ? pr[4 * ks2 + 2] : pk[4 * ks2 + 0];
            pf.u[1] = h32 ? pr[4 * ks2 + 3] : pk[4 * ks2 + 1];
            pf.u[2] = h32 ? pk[4 * ks2 + 2] : pr[4 * ks2 + 0];
            pf.u[3] = h32 ? pk[4 * ks2 + 3] : pr[4 * ks2 + 1];
            #pragma unroll
            for (int db = 0; db < 2; ++db) {
                bf16x8 vf = *(const bf16x8*)(Vt + (db * 32 + l31) * 72 + kbase + ks2 * 16 + h32 * 8);
                accOT[db] = __builtin_amdgcn_mfma_f32_32x32x16_bf16(vf, pf.b, accOT[db], 0, 0, 0);
            }
        }
    }

    float l_s = (la[0] + la[1]) + (la[2] + la[3]);

    __syncthreads();
    float* exO = (qhalf == 0) ? (float*)Ks : (float*)Vt;   // 64 lanes x 36 floats
    if (khalf == 1) {
        #pragma unroll
        for (int db = 0; db < 2; ++db)
            #pragma unroll
            for (int c = 0; c < 4; ++c) {
                float4 v = { accOT[db][c*4], accOT[db][c*4+1], accOT[db][c*4+2], accOT[db][c*4+3] };
                *(float4*)(exO + lane * 36 + db * 16 + c * 4) = v;
            }
        exO[lane * 36 + 32] = l_s;
    }
    __syncthreads();
    float inv = 0.f;
    if (khalf == 0) {
        #pragma unroll
        for (int db = 0; db < 2; ++db)
            #pragma unroll
            for (int c = 0; c < 4; ++c) {
                float4 v = *(const float4*)(exO + lane * 36 + db * 16 + c * 4);
                accOT[db][c*4]   += v.x; accOT[db][c*4+1] += v.y;
                accOT[db][c*4+2] += v.z; accOT[db][c*4+3] += v.w;
            }
        l_s += exO[lane * 36 + 32];
        l_s += __shfl_xor(l_s, 32, 64);   // other h32 half of the same q
        inv = 1.f / l_s;
    }
    __syncthreads();   // merge reads done; Ks free for the transpose tile

    unsigned short* Ot = Ks;   // [64][68] u16
    if (khalf == 0) {
        const int row = qhalf * 32 + l31;
        #pragma unroll
        for (int db = 0; db < 2; ++db)
            #pragma unroll
            for (int c = 0; c < 4; ++c) {
                unsigned int w0 = pack2bf(accOT[db][4*c]   * inv, accOT[db][4*c+1] * inv);
                unsigned int w1 = pack2bf(accOT[db][4*c+2] * inv, accOT[db][4*c+3] * inv);
                const int off = db * 32 + 8 * c + 4 * h32;
                *(unsigned int*)(Ot + row * 68 + off)     = w0;
                *(unsigned int*)(Ot + row * 68 + off + 2) = w1;
            }
    }
    __syncthreads();
    {
        const int row = t >> 2, col = (t & 3) * 16;
        uint4 o0 = *(const uint4*)(Ot + row * 68 + col);
        uint4 o1 = *(const uint4*)(Ot + row * 68 + col + 8);
        unsigned short* dst = Om + (size_t)(b * SEQ + qt * 64 + row) * D_MODEL + h * DKH + col;
        *(uint4*)(dst)     = o0;
        *(uint4*)(dst + 8) = o1;
    }
}

extern "C" void kernel_launch(void* const* d_in, const int* in_sizes, int n_in,
                              void* d_out, int out_size, void* d_ws, size_t ws_size,
                              hipStream_t stream) {
    const float* x   = (const float*)d_in[0];
    const float* w_q = (const float*)d_in[1];
    const float* w_k = (const float*)d_in[2];
    const float* w_v = (const float*)d_in[3];
    const float* w_o = (const float*)d_in[4];
    float* out = (float*)d_out;

    // ws (48 MB): xb 8 | weights 4x2 | Qb 8 | Kb 8 | VtG 8 | Ab 8
    unsigned short* xb  = (unsigned short*)d_ws;
    unsigned short* wqb = xb  + (size_t)MTOT * D_MODEL;
    unsigned short* wkb = wqb + (size_t)D_MODEL * D_MODEL;
    unsigned short* wvb = wkb + (size_t)D_MODEL * D_MODEL;
    unsigned short* wob = wvb + (size_t)D_MODEL * D_MODEL;
    unsigned short* Qb  = wob + (size_t)D_MODEL * D_MODEL;
    unsigned short* Kb  = Qb  + (size_t)MTOT * D_MODEL;
    unsigned short* VtG = Kb  + (size_t)MTOT * D_MODEL;   // V^T [1024][4096]
    unsigned short* Ab  = VtG + (size_t)MTOT * D_MODEL;

    cvt_all<<<dim3(2048 + 4 * 512), dim3(256), 0, stream>>>(
        x, w_q, w_k, w_v, w_o, xb, wqb, wkb, wvb, wob);
    // fused QKV projection: 128x64 tiles, 512 blocks = 2/CU.
    // Q scale = (1/8) * log2(e) so attention can use exp2.
    qkv_fused<<<dim3(512), dim3(256), 0, stream>>>(
        xb, wqb, wkb, wvb, Qb, Kb, VtG, 0.125f * 1.44269504f);
    // balanced causal flash attention (r5-exact verified structure)
    attn_kernel<<<dim3(BATCH * NHEADS, 32), dim3(256), 0, stream>>>(Qb, Kb, VtG, Ab);
    // output projection -> fp32 (depth-2 counted-vmcnt pipeline, literal buf idx)
    gemm_o<<<dim3(MTOT / 128, D_MODEL / 128), dim3(512), 0, stream>>>(Ab, wob, out);
}

// Round 10
// 160.929 us; speedup vs baseline: 1.0188x; 1.0188x over previous
//
#include <hip/hip_runtime.h>
#include <hip/hip_bf16.h>
#include <stdint.h>

#define D_MODEL 1024
#define NHEADS  16
#define DKH     64
#define BATCH   2
#define SEQ     2048
#define MTOT    (BATCH*SEQ)   // 4096

typedef __attribute__((ext_vector_type(8)))  short bf16x8;   // 8 bf16 = 4 VGPRs
typedef __attribute__((ext_vector_type(4)))  float f32x4;
typedef __attribute__((ext_vector_type(16))) float f32x16;
typedef __attribute__((ext_vector_type(4)))  unsigned int u32x4;

__device__ inline unsigned short f2bf(float f) {
    __hip_bfloat16 h = __float2bfloat16(f);
    return *reinterpret_cast<unsigned short*>(&h);
}
__device__ inline unsigned int pack2bf(float a, float b) {   // low=a, high=b (RNE)
    __hip_bfloat162 h = __float22bfloat162_rn(float2{a, b});
    return *reinterpret_cast<unsigned int*>(&h);
}

// async global->LDS, 16B per lane; LDS dest = wave-uniform base + lane*16 (m97/m104)
__device__ inline void gl2lds16(const unsigned short* g, unsigned short* l) {
    __builtin_amdgcn_global_load_lds(
        (const __attribute__((address_space(1))) void*)g,
        (__attribute__((address_space(3))) void*)l,
        16, 0, 0);
}

// One-shot fp32 -> bf16 conversion of x and the 4 weight matrices.
__global__ __launch_bounds__(256) void cvt_all(
    const float* __restrict__ x,  const float* __restrict__ wq,
    const float* __restrict__ wk, const float* __restrict__ wv,
    const float* __restrict__ wo,
    unsigned short* __restrict__ xb,  unsigned short* __restrict__ wqb,
    unsigned short* __restrict__ wkb, unsigned short* __restrict__ wvb,
    unsigned short* __restrict__ wob)
{
    int bid = blockIdx.x;
    const float* s; unsigned short* d; size_t base;
    if (bid < 2048) { s = x; d = xb; base = (size_t)bid * 2048; }
    else {
        int w  = (bid - 2048) >> 9;
        int wb = (bid - 2048) & 511;
        s = (w == 0) ? wq : (w == 1) ? wk : (w == 2) ? wv : wo;
        d = (w == 0) ? wqb : (w == 1) ? wkb : (w == 2) ? wvb : wob;
        base = (size_t)wb * 2048;
    }
    size_t i = base + (size_t)threadIdx.x * 8;
    float4 a = *(const float4*)(s + i);
    float4 b = *(const float4*)(s + i + 4);
    unsigned short t8[8] = {f2bf(a.x), f2bf(a.y), f2bf(a.z), f2bf(a.w),
                            f2bf(b.x), f2bf(b.y), f2bf(b.z), f2bf(b.w)};
    *(uint4*)(d + i) = *(uint4*)t8;
}

// Fused QKV projection, depth-2 counted-vmcnt pipeline, literal buffer
// indices (r8-exact — best measured config, <=42us; r9's 2-block retile was
// neutral: staging-rate law ~9.6 B/cyc/CU gains only ~+3/extra block while
// bytes scale with 1/BN — geometry changes self-defeat in this regime).
__global__ __launch_bounds__(512, 2) void qkv_fused(
    const unsigned short* __restrict__ X,
    const unsigned short* __restrict__ Wq,
    const unsigned short* __restrict__ Wk,
    const unsigned short* __restrict__ Wv,
    unsigned short* __restrict__ Qo,
    unsigned short* __restrict__ Ko,
    unsigned short* __restrict__ Vto,
    float qscale)
{
    const int id = blockIdx.x + 32 * blockIdx.y;   // 256 blocks, 256%8==0
    const int sw = (id & 7) * 32 + (id >> 3);      // XCD c -> contiguous chunk
    const int m0 = (sw & 31) * 128;                // x-row tile
    const int n0 = (sw >> 5) * 128;                // weight-row tile

    __shared__ __align__(16) unsigned short Xs[3][128 * 32];
    __shared__ __align__(16) unsigned short Bq[3][128 * 32];
    __shared__ __align__(16) unsigned short Bk[3][128 * 32];
    __shared__ __align__(16) unsigned short Bv[3][128 * 32];

    const int t = threadIdx.x;
    const int wave = t >> 6, lane = t & 63;
    const int quad = lane >> 4, l16 = lane & 15;
    const int wm = (wave >> 2) * 64;
    const int wn = (wave & 3) * 32;

    const int stile = wave >> 1;
    const int srow  = (wave & 1) * 64 + (lane >> 2);
    const int schk  = (lane & 3) * 8;
    const unsigned short* gsrc = (stile == 0) ? X : (stile == 1) ? Wq :
                                 (stile == 2) ? Wk : Wv;
    const int grow0 = (stile == 0) ? m0 : n0;
    const unsigned short* Sg = gsrc + (size_t)(grow0 + srow) * D_MODEL + schk;
    unsigned short* LdB = ((stile == 0) ? &Xs[0][0] : (stile == 1) ? &Bq[0][0] :
                           (stile == 2) ? &Bk[0][0] : &Bv[0][0])
                          + (wave & 1) * 64 * 32;   // wave-uniform base

    f32x4 aQ[4][2] = {}, aK[4][2] = {}, aV[2][4] = {};

#define QKV_STAGE(BUF, STEP)                                                  \
    do {                                                                      \
        _Pragma("unroll")                                                     \
        for (int g = 0; g < 4; ++g)                                           \
            gl2lds16(Sg + (STEP) * 32 + (size_t)g * 16 * D_MODEL,             \
                     LdB + (BUF) * 4096 + g * 512);                           \
    } while (0)

#define QKV_COMP(BUF)                                                         \
    do {                                                                      \
        bf16x8 xa[4], fq[2], fk[2], fv[2];                                    \
        _Pragma("unroll")                                                     \
        for (int i = 0; i < 4; ++i)                                           \
            xa[i] = *(const bf16x8*)(&Xs[(BUF)][0] + (wm + i * 16 + l16) * 32 + quad * 8); \
        _Pragma("unroll")                                                     \
        for (int j = 0; j < 2; ++j) {                                         \
            fq[j] = *(const bf16x8*)(&Bq[(BUF)][0] + (wn + j * 16 + l16) * 32 + quad * 8); \
            fk[j] = *(const bf16x8*)(&Bk[(BUF)][0] + (wn + j * 16 + l16) * 32 + quad * 8); \
            fv[j] = *(const bf16x8*)(&Bv[(BUF)][0] + (wn + j * 16 + l16) * 32 + quad * 8); \
        }                                                                     \
        _Pragma("unroll")                                                     \
        for (int i = 0; i < 4; ++i)                                           \
            _Pragma("unroll")                                                 \
            for (int j = 0; j < 2; ++j) {                                     \
                aQ[i][j] = __builtin_amdgcn_mfma_f32_16x16x32_bf16(xa[i], fq[j], aQ[i][j], 0, 0, 0); \
                aK[i][j] = __builtin_amdgcn_mfma_f32_16x16x32_bf16(xa[i], fk[j], aK[i][j], 0, 0, 0); \
                aV[j][i] = __builtin_amdgcn_mfma_f32_16x16x32_bf16(fv[j], xa[i], aV[j][i], 0, 0, 0); \
            }                                                                 \
    } while (0)

#define QKV_STEP(CBUF, SBUF, STEP)                                            \
    do {                                                                      \
        __builtin_amdgcn_s_barrier();                                         \
        QKV_STAGE(SBUF, (STEP) + 2);                                          \
        asm volatile("s_waitcnt vmcnt(8)" ::: "memory");                      \
        __builtin_amdgcn_s_barrier();                                         \
        __builtin_amdgcn_sched_barrier(0);                                    \
        QKV_COMP(CBUF);                                                       \
    } while (0)

    QKV_STAGE(0, 0);
    QKV_STAGE(1, 1);
    for (int s3 = 0; s3 < 30; s3 += 3) {
        QKV_STEP(0, 2, s3);
        QKV_STEP(1, 0, s3 + 1);
        QKV_STEP(2, 1, s3 + 2);
    }
    __builtin_amdgcn_s_barrier();
    asm volatile("s_waitcnt vmcnt(4)" ::: "memory");
    __builtin_amdgcn_s_barrier();
    __builtin_amdgcn_sched_barrier(0);
    QKV_COMP(0);
    __builtin_amdgcn_s_barrier();
    asm volatile("s_waitcnt vmcnt(0)" ::: "memory");
    __builtin_amdgcn_s_barrier();
    __builtin_amdgcn_sched_barrier(0);
    QKV_COMP(1);
#undef QKV_STEP
#undef QKV_STAGE
#undef QKV_COMP

    #pragma unroll
    for (int i = 0; i < 4; ++i)
        #pragma unroll
        for (int j = 0; j < 2; ++j)
            #pragma unroll
            for (int r = 0; r < 4; ++r) {
                const int mr = m0 + wm + i * 16 + quad * 4 + r;
                const int nc = n0 + wn + j * 16 + l16;
                Qo[(size_t)mr * D_MODEL + nc] = f2bf(aQ[i][j][r] * qscale);
                Ko[(size_t)mr * D_MODEL + nc] = f2bf(aK[i][j][r]);
                // V^T: row = weight-side of aV, col = x-side
                Vto[(size_t)(n0 + wn + j * 16 + quad * 4 + r) * MTOT
                    + (m0 + wm + i * 16 + l16)] = f2bf(aV[j][i][r]);
            }
}

// Output projection C_fp32[M,N] = A[M,K] @ W[N,K]^T (r8-exact, ~21us).
__global__ __launch_bounds__(512, 2) void gemm_o(
    const unsigned short* __restrict__ A,
    const unsigned short* __restrict__ W,
    float* __restrict__ C)
{
    const int id = blockIdx.x + 32 * blockIdx.y;
    const int sw = (id & 7) * 32 + (id >> 3);
    const int m0 = (sw & 31) * 128, n0 = (sw >> 5) * 128;

    __shared__ __align__(16) unsigned short As[3][128 * 32];
    __shared__ __align__(16) unsigned short Bs[3][128 * 32];   // 48 KiB

    const int t = threadIdx.x, wave = t >> 6, lane = t & 63;
    const int quad = lane >> 4, l16 = lane & 15;
    const int wm = (wave >> 2) * 64, wn = (wave & 3) * 32;

    const int stile = wave >> 2;
    const int srow  = (wave & 3) * 32 + (lane >> 2);
    const int schk  = (lane & 3) * 8;
    const unsigned short* Sg = (stile ? W : A)
        + (size_t)((stile ? n0 : m0) + srow) * D_MODEL + schk;
    unsigned short* LdB = (stile ? &Bs[0][0] : &As[0][0]) + (wave & 3) * 32 * 32;

    f32x4 acc[4][2] = {};

#define O_STAGE(BUF, STEP)                                                    \
    do {                                                                      \
        _Pragma("unroll")                                                     \
        for (int g = 0; g < 2; ++g)                                           \
            gl2lds16(Sg + (STEP) * 32 + (size_t)g * 16 * D_MODEL,             \
                     LdB + (BUF) * 4096 + g * 512);                           \
    } while (0)

#define O_COMP(BUF)                                                           \
    do {                                                                      \
        bf16x8 af[4], bfr[2];                                                 \
        _Pragma("unroll")                                                     \
        for (int i = 0; i < 4; ++i)                                           \
            af[i] = *(const bf16x8*)(&As[(BUF)][0] + (wm + i * 16 + l16) * 32 + quad * 8); \
        _Pragma("unroll")                                                     \
        for (int j = 0; j < 2; ++j)                                           \
            bfr[j] = *(const bf16x8*)(&Bs[(BUF)][0] + (wn + j * 16 + l16) * 32 + quad * 8); \
        _Pragma("unroll")                                                     \
        for (int i = 0; i < 4; ++i)                                           \
            _Pragma("unroll")                                                 \
            for (int j = 0; j < 2; ++j)                                       \
                acc[i][j] = __builtin_amdgcn_mfma_f32_16x16x32_bf16(af[i], bfr[j], acc[i][j], 0, 0, 0); \
    } while (0)

#define O_STEP(CBUF, SBUF, STEP)                                              \
    do {                                                                      \
        __builtin_amdgcn_s_barrier();                                         \
        O_STAGE(SBUF, (STEP) + 2);                                            \
        asm volatile("s_waitcnt vmcnt(4)" ::: "memory");                      \
        __builtin_amdgcn_s_barrier();                                         \
        __builtin_amdgcn_sched_barrier(0);                                    \
        O_COMP(CBUF);                                                         \
    } while (0)

    O_STAGE(0, 0);
    O_STAGE(1, 1);
    for (int s3 = 0; s3 < 30; s3 += 3) {
        O_STEP(0, 2, s3);
        O_STEP(1, 0, s3 + 1);
        O_STEP(2, 1, s3 + 2);
    }
    __builtin_amdgcn_s_barrier();
    asm volatile("s_waitcnt vmcnt(2)" ::: "memory");
    __builtin_amdgcn_s_barrier();
    __builtin_amdgcn_sched_barrier(0);
    O_COMP(0);
    __builtin_amdgcn_s_barrier();
    asm volatile("s_waitcnt vmcnt(0)" ::: "memory");
    __builtin_amdgcn_s_barrier();
    __builtin_amdgcn_sched_barrier(0);
    O_COMP(1);
#undef O_STEP
#undef O_STAGE
#undef O_COMP

    #pragma unroll
    for (int i = 0; i < 4; ++i)
        #pragma unroll
        for (int j = 0; j < 2; ++j)
            #pragma unroll
            for (int r = 0; r < 4; ++r)
                C[(size_t)(m0 + wm + i * 16 + quad * 4 + r) * D_MODEL
                  + n0 + wn + j * 16 + l16] = acc[i][j][r];
}

// Flash causal attention — r5/r8 verified structure with ONE change:
// the softmax row-sum l moves from the VALU (16 serial v_add_f32 per tile,
// on the 44%-busy pipe) to the 15%-idle MFMA pipe: l[q] = ones_row . P^T via
// one extra mfma per ks2-half accumulating into accL. accL's C-layout has
// col=l31=q and ALL rows identical (A=ones), so l_s = accL[0] per lane and
// the h32 shfl disappears (the MFMA sums all 16 k of the instruction).
// l now sums the bf16-quantized p values — the same values PV uses.
__global__ __launch_bounds__(256, 4) void attn_kernel(
    const unsigned short* __restrict__ Qm,
    const unsigned short* __restrict__ Km,
    const unsigned short* __restrict__ VtG,
    unsigned short* __restrict__ Om)
{
    const int bh = blockIdx.x;
    const int y  = blockIdx.y, g = y & 7, sl = y >> 3;
    const int qt = (sl == 0) ? 31 - g : (sl == 1) ? 16 + g : (sl == 2) ? 15 - g : g;
    const int h  = bh & 15;
    const int b  = bh >> 4;
    const int t     = threadIdx.x;
    const int wave  = t >> 6, lane = t & 63;
    const int qhalf = wave >> 1, khalf = wave & 1;
    const int l31   = lane & 31, h32 = lane >> 5;

    __shared__ __align__(16) unsigned short Ks[64 * 72];      // K tile [key][dk]
    __shared__ __align__(16) unsigned short Vt[64 * 72];      // V^T tile [dk][key]

    const size_t base = (size_t)b * SEQ * D_MODEL + (size_t)h * DKH;
    const unsigned short* Qh = Qm + base;
    const unsigned short* Kh = Km + base;
    const unsigned short* Vh = VtG + (size_t)h * DKH * MTOT + (size_t)b * SEQ;  // [dk][m]

    const int qrow = qt * 64 + qhalf * 32 + l31;
    bf16x8 qf[4];
    #pragma unroll
    for (int ks = 0; ks < 4; ++ks)
        qf[ks] = *(const bf16x8*)(Qh + (size_t)qrow * D_MODEL + ks * 16 + h32 * 8);

    // bf16 1.0 = 0x3F80 in every element: A-operand "ones" for the l-row MFMA
    const short one_bf = (short)0x3F80;
    const bf16x8 onesf = {one_bf, one_bf, one_bf, one_bf,
                          one_bf, one_bf, one_bf, one_bf};

    f32x16 accOT[2] = {};   // O^T partial: col=l31=q, row=(reg&3)+8*(reg>>2)+4*h32=dk (+32*db)
    f32x16 accL = {};       // l partial: col=l31=q, all rows identical (A=ones)

    const int srow = t >> 2, scol = (t & 3) * 16;
    const int kbase = khalf * 32;

    uint4 kr0, kr1, vr0, vr1;
    {
        const unsigned short* ks = Kh + (size_t)srow * D_MODEL + scol;
        kr0 = *(const uint4*)ks; kr1 = *(const uint4*)(ks + 8);
        const unsigned short* vs = Vh + (size_t)srow * MTOT + scol;
        vr0 = *(const uint4*)vs; vr1 = *(const uint4*)(vs + 8);
    }

    for (int kt = 0; kt <= qt; ++kt) {
        __syncthreads();   // prior iter's frag reads done
        *(uint4*)(Ks + srow * 72 + scol)     = kr0;
        *(uint4*)(Ks + srow * 72 + scol + 8) = kr1;
        *(uint4*)(Vt + srow * 72 + scol)     = vr0;
        *(uint4*)(Vt + srow * 72 + scol + 8) = vr1;
        __syncthreads();

        if (kt < qt) {     // prefetch next tile; overlaps compute below
            const unsigned short* ks = Kh + (size_t)((kt + 1) * 64 + srow) * D_MODEL + scol;
            kr0 = *(const uint4*)ks; kr1 = *(const uint4*)(ks + 8);
            const unsigned short* vs = Vh + (size_t)srow * MTOT + (kt + 1) * 64 + scol;
            vr0 = *(const uint4*)vs; vr1 = *(const uint4*)(vs + 8);
        }

        const bool diag = (kt == qt);
        if (diag && khalf > qhalf) continue;   // fully-masked quarter: skip

        // S^T = K Q^T : A=K rows
        f32x16 sT = {};
        #pragma unroll
        for (int ks = 0; ks < 4; ++ks) {
            bf16x8 kf = *(const bf16x8*)(Ks + (kbase + l31) * 72 + ks * 16 + h32 * 8);
            sT = __builtin_amdgcn_mfma_f32_32x32x16_bf16(kf, qf[ks], sT, 0, 0, 0);
        }

        // p = exp2(s); mask on equal-half diag quarter: keep key(rloc) <= q(l31)
        const bool maskq = diag && (khalf == qhalf);
        float pv[16];
        #pragma unroll
        for (int reg = 0; reg < 16; ++reg) {
            const int rloc = (reg & 3) + 8 * (reg >> 2) + 4 * h32;   // key_local
            float v = sT[reg];
            if (maskq) v = (rloc <= l31) ? v : -1e30f;
            pv[reg] = exp2f(v);
        }
        // pack pairs (consecutive regs = consecutive keys) and half-wave exchange
        unsigned int pk[8], pr[8];
        #pragma unroll
        for (int i = 0; i < 8; ++i) pk[i] = pack2bf(pv[2 * i], pv[2 * i + 1]);
        #pragma unroll
        for (int i = 0; i < 8; ++i) pr[i] = __shfl_xor(pk[i], 32, 64);

        // O^T += V^T P^T (A = V^T rows, B = P^T in regs); l += ones . P^T
        #pragma unroll
        for (int ks2 = 0; ks2 < 2; ++ks2) {
            union { u32x4 u; bf16x8 b; } pf;
            pf.u[0] = h32 ? pr[4 * ks2 + 2] : pk[4 * ks2 + 0];
            pf.u[1] = h32 ? pr[4 * ks2 + 3] : pk[4 * ks2 + 1];
            pf.u[2] = h32 ? pk[4 * ks2 + 2] : pr[4 * ks2 + 0];
            pf.u[3] = h32 ? pk[4 * ks2 + 3] : pr[4 * ks2 + 1];
            accL = __builtin_amdgcn_mfma_f32_32x32x16_bf16(onesf, pf.b, accL, 0, 0, 0);
            #pragma unroll
            for (int db = 0; db < 2; ++db) {
                bf16x8 vf = *(const bf16x8*)(Vt + (db * 32 + l31) * 72 + kbase + ks2 * 16 + h32 * 8);
                accOT[db] = __builtin_amdgcn_mfma_f32_32x32x16_bf16(vf, pf.b, accOT[db], 0, 0, 0);
            }
        }
    }

    float l_s = accL[0];   // sum over this wave's keys for q=l31 (all regs equal)

    // ---- merge key halves (khalf 1 -> 0) through dead Ks/Vt ----
    __syncthreads();
    float* exO = (qhalf == 0) ? (float*)Ks : (float*)Vt;   // 64 lanes x 36 floats
    if (khalf == 1) {
        #pragma unroll
        for (int db = 0; db < 2; ++db)
            #pragma unroll
            for (int c = 0; c < 4; ++c) {
                float4 v = { accOT[db][c*4], accOT[db][c*4+1], accOT[db][c*4+2], accOT[db][c*4+3] };
                *(float4*)(exO + lane * 36 + db * 16 + c * 4) = v;
            }
        exO[lane * 36 + 32] = l_s;
    }
    __syncthreads();
    float inv = 0.f;
    if (khalf == 0) {
        #pragma unroll
        for (int db = 0; db < 2; ++db)
            #pragma unroll
            for (int c = 0; c < 4; ++c) {
                float4 v = *(const float4*)(exO + lane * 36 + db * 16 + c * 4);
                accOT[db][c*4]   += v.x; accOT[db][c*4+1] += v.y;
                accOT[db][c*4+2] += v.z; accOT[db][c*4+3] += v.w;
            }
        l_s += exO[lane * 36 + 32];
        inv = 1.f / l_s;   // no h32 shfl: accL already sums all 16 k per instr
    }
    __syncthreads();   // merge reads done; Ks free for the transpose tile

    // ---- transpose O^T -> [q][dk] bf16 tile in Ks, then coalesced store ----
    unsigned short* Ot = Ks;   // [64][68] u16
    if (khalf == 0) {
        const int row = qhalf * 32 + l31;
        #pragma unroll
        for (int db = 0; db < 2; ++db)
            #pragma unroll
            for (int c = 0; c < 4; ++c) {
                unsigned int w0 = pack2bf(accOT[db][4*c]   * inv, accOT[db][4*c+1] * inv);
                unsigned int w1 = pack2bf(accOT[db][4*c+2] * inv, accOT[db][4*c+3] * inv);
                const int off = db * 32 + 8 * c + 4 * h32;
                *(unsigned int*)(Ot + row * 68 + off)     = w0;
                *(unsigned int*)(Ot + row * 68 + off + 2) = w1;
            }
    }
    __syncthreads();
    {
        const int row = t >> 2, col = (t & 3) * 16;
        uint4 o0 = *(const uint4*)(Ot + row * 68 + col);
        uint4 o1 = *(const uint4*)(Ot + row * 68 + col + 8);
        unsigned short* dst = Om + (size_t)(b * SEQ + qt * 64 + row) * D_MODEL + h * DKH + col;
        *(uint4*)(dst)     = o0;
        *(uint4*)(dst + 8) = o1;
    }
}

extern "C" void kernel_launch(void* const* d_in, const int* in_sizes, int n_in,
                              void* d_out, int out_size, void* d_ws, size_t ws_size,
                              hipStream_t stream) {
    const float* x   = (const float*)d_in[0];
    const float* w_q = (const float*)d_in[1];
    const float* w_k = (const float*)d_in[2];
    const float* w_v = (const float*)d_in[3];
    const float* w_o = (const float*)d_in[4];
    float* out = (float*)d_out;

    // ws (48 MB): xb 8 | weights 4x2 | Qb 8 | Kb 8 | VtG 8 | Ab 8
    unsigned short* xb  = (unsigned short*)d_ws;
    unsigned short* wqb = xb  + (size_t)MTOT * D_MODEL;
    unsigned short* wkb = wqb + (size_t)D_MODEL * D_MODEL;
    unsigned short* wvb = wkb + (size_t)D_MODEL * D_MODEL;
    unsigned short* wob = wvb + (size_t)D_MODEL * D_MODEL;
    unsigned short* Qb  = wob + (size_t)D_MODEL * D_MODEL;
    unsigned short* Kb  = Qb  + (size_t)MTOT * D_MODEL;
    unsigned short* VtG = Kb  + (size_t)MTOT * D_MODEL;   // V^T [1024][4096]
    unsigned short* Ab  = VtG + (size_t)MTOT * D_MODEL;

    cvt_all<<<dim3(2048 + 4 * 512), dim3(256), 0, stream>>>(
        x, w_q, w_k, w_v, w_o, xb, wqb, wkb, wvb, wob);
    // fused QKV projection (r8-exact). Q scale = (1/8)*log2(e) for exp2.
    qkv_fused<<<dim3(MTOT / 128, D_MODEL / 128), dim3(512), 0, stream>>>(
        xb, wqb, wkb, wvb, Qb, Kb, VtG, 0.125f * 1.44269504f);
    // balanced causal flash attention (l-row via MFMA-ones)
    attn_kernel<<<dim3(BATCH * NHEADS, 32), dim3(256), 0, stream>>>(Qb, Kb, VtG, Ab);
    // output projection -> fp32 (r8-exact)
    gemm_o<<<dim3(MTOT / 128, D_MODEL / 128), dim3(512), 0, stream>>>(Ab, wob, out);
}